// Round 1
// baseline (15143.736 us; speedup 1.0000x reference)
//
#include <hip/hip_runtime.h>
#include <math.h>

#define NDIM 4096
#define NR 4095          // rounds = N-1
#define NPAIRS 2048      // N/2
#define CB 8             // columns per workgroup (N*CB*4 = 128 KB LDS)
#define NTHREADS 256
#define PPT (NPAIRS / NTHREADS)   // 8 pairs per thread per round

// LDS layout: 16B half h (cols 4h..4h+3) of row x at float offset
// 8*x + 4*(h ^ ((x>>2)&1)).  Quad-XOR swizzle: any 8 consecutive rows map
// their halves onto all 8 bank-quads -> conflict-free b128 for the
// lane-consecutive row pattern of the tournament schedule.
__device__ __forceinline__ int half_off(int x, int h) {
    return x * 8 + ((h ^ ((x >> 2) & 1)) << 2);
}

__global__ void cs_precompute(const float* __restrict__ thetas,
                              const int* __restrict__ round_theta,
                              float2* __restrict__ cs, int total) {
    int idx = blockIdx.x * blockDim.x + threadIdx.x;
    if (idx < total) {
        float th = thetas[round_theta[idx]];
        float s, c;
        sincosf(th, &s, &c);
        cs[idx] = make_float2(c, s);
    }
}

__device__ __forceinline__ void rot4(float c, float s,
                                     const float4& a, const float4& b,
                                     float4& na, float4& nb) {
    na.x = c * a.x - s * b.x;  nb.x = s * a.x + c * b.x;
    na.y = c * a.y - s * b.y;  nb.y = s * a.y + c * b.y;
    na.z = c * a.z - s * b.z;  nb.z = s * a.z + c * b.z;
    na.w = c * a.w - s * b.w;  nb.w = s * a.w + c * b.w;
}

template <bool USE_CS>
__global__ __launch_bounds__(NTHREADS, 1)
void rotmat_apply(const float2* __restrict__ cs,
                  const float* __restrict__ thetas,
                  float* __restrict__ out) {
    __shared__ float U[NDIM * CB];   // 128 KB column slice of U
    const int tid  = threadIdx.x;
    const int col0 = blockIdx.x * CB;

    // identity init: U[x][c] = (x == col0 + c)
    for (int x = tid; x < NDIM; x += NTHREADS) {
#pragma unroll
        for (int h = 0; h < 2; ++h) {
            float4 v = make_float4(0.f, 0.f, 0.f, 0.f);
            int d = x - (col0 + 4 * h);
            if (d >= 0 && d < 4) (&v.x)[d] = 1.0f;
            *(float4*)&U[half_off(x, h)] = v;
        }
    }
    __syncthreads();

    float2 csCur[PPT], csNext[PPT];
    if (USE_CS) {
#pragma unroll
        for (int m = 0; m < PPT; ++m)
            csCur[m] = cs[tid + m * NTHREADS];
    }

    for (int r = 0; r < NR; ++r) {
        // prefetch next round's (c,s) while this round computes
        if (USE_CS && (r + 1 < NR)) {
            const float2* csr = cs + (size_t)(r + 1) * NPAIRS;
#pragma unroll
            for (int m = 0; m < PPT; ++m)
                csNext[m] = csr[tid + m * NTHREADS];
        }
#pragma unroll
        for (int m = 0; m < PPT; ++m) {
            int k = tid + m * NTHREADS;
            // tournament closed form (matches reference _schedule):
            //   pair 0: (r, N-1); pair k: ((r+k) % (N-1), (r-k) % (N-1))
            int x = r + k; if (x >= NR) x -= NR;
            int y = r - k; if (y < 0) y += NR;
            if (k == 0) y = NDIM - 1;
            int i = (x < y) ? x : y;
            int j = (x < y) ? y : x;

            float c, s;
            if (USE_CS) {
                c = csCur[m].x; s = csCur[m].y;
            } else {
                int t = i * NDIM - (i * (i + 1)) / 2 + (j - i - 1);
                float th = thetas[t];
                sincosf(th, &s, &c);
            }

            float4 a0 = *(float4*)&U[half_off(i, 0)];
            float4 a1 = *(float4*)&U[half_off(i, 1)];
            float4 b0 = *(float4*)&U[half_off(j, 0)];
            float4 b1 = *(float4*)&U[half_off(j, 1)];
            float4 na0, na1, nb0, nb1;
            rot4(c, s, a0, b0, na0, nb0);
            rot4(c, s, a1, b1, na1, nb1);
            *(float4*)&U[half_off(i, 0)] = na0;
            *(float4*)&U[half_off(i, 1)] = na1;
            *(float4*)&U[half_off(j, 0)] = nb0;
            *(float4*)&U[half_off(j, 1)] = nb1;
        }
        __syncthreads();
        if (USE_CS) {
#pragma unroll
            for (int m = 0; m < PPT; ++m) csCur[m] = csNext[m];
        }
    }

    // write the column slice to global (row-major out[N][N])
    for (int x = tid; x < NDIM; x += NTHREADS) {
        float4 a = *(float4*)&U[half_off(x, 0)];
        float4 b = *(float4*)&U[half_off(x, 1)];
        float4* o = (float4*)&out[(size_t)x * NDIM + col0];
        o[0] = a;
        o[1] = b;
    }
}

extern "C" void kernel_launch(void* const* d_in, const int* in_sizes, int n_in,
                              void* d_out, int out_size, void* d_ws, size_t ws_size,
                              hipStream_t stream) {
    const float* thetas      = (const float*)d_in[0];
    const int*   round_theta = (const int*)d_in[3];
    float*       out         = (float*)d_out;

    const int total = NR * NPAIRS;
    const size_t need = (size_t)total * sizeof(float2);

    if (ws_size >= need) {
        float2* cs = (float2*)d_ws;
        cs_precompute<<<(total + 255) / 256, 256, 0, stream>>>(
            thetas, round_theta, cs, total);
        rotmat_apply<true><<<NDIM / CB, NTHREADS, 0, stream>>>(cs, thetas, out);
    } else {
        // workspace too small: compute sin/cos inline (slower fallback)
        rotmat_apply<false><<<NDIM / CB, NTHREADS, 0, stream>>>(nullptr, thetas, out);
    }
}

// Round 2
// 6431.837 us; speedup vs baseline: 2.3545x; 2.3545x over previous
//
#include <hip/hip_runtime.h>
#include <math.h>

#define NDIM 4096
#define NR   4095        // rounds = N-1 (also = number of rotating positions)
#define NPAIRS 2048      // N/2 tables
#define CB   8           // columns per workgroup slice
#define NTHREADS 256
#define TPT  8           // tables per thread (NPAIRS / NTHREADS)

// Precompute (c, s) per (round, table); bake in the orientation sign:
// table k at round r holds players a=(r+k)%NR (top) and b=(r-k)%NR (bottom,
// or 4095 fixed for k=0). Reference rotates (i,j)=(min,max) with
// U[i]=c*Ui-s*Uj, U[j]=s*Ui+c*Uj. If top==j the update is equivalent to
// negating s. top>bottom iff 0<k<=r<NR-k.
__global__ void cs_precompute(const float* __restrict__ thetas,
                              const int* __restrict__ round_theta,
                              float2* __restrict__ cs, int total) {
    int idx = blockIdx.x * blockDim.x + threadIdx.x;
    if (idx >= total) return;
    int r = idx / NPAIRS;
    int k = idx - r * NPAIRS;
    float th = thetas[round_theta[idx]];
    float s, c;
    sincosf(th, &s, &c);
    if (k > 0 && k <= r && r < NR - k) s = -s;
    cs[idx] = make_float2(c, s);
}

// Register-systolic circle method. Seats: top[g]=position g (g=0..2047),
// bottom[g]=position 4095-g (g>=1), bottom[0]=fixed player 4095.
// Each round: rotate each table (top[g],bot[g]) then shift ring by -1:
//   top[g] <- na(g+1); top[2047] <- nb(2047)
//   bot[g] <- nb(g-1) (g>=2); bot[1] <- na(0); bot[0] <- nb(0) (fixed seat)
// Thread t owns tables 8t..8t+7; only na(table 8t) and nb(table 8t+7) cross
// threads (shfl by 1 lane; LDS double-buffer at wave boundaries).
template<bool USE_CS>
__global__ __launch_bounds__(NTHREADS, 2)
void rotmat_systolic(const float2* __restrict__ cs,
                     const float* __restrict__ thetas,
                     float* __restrict__ out) {
    __shared__ float naBuf[2][4][CB];   // written by lane0 of each wave
    __shared__ float nbBuf[2][4][CB];   // written by lane63 of each wave

    const int tid  = threadIdx.x;
    const int lane = tid & 63;
    const int wave = tid >> 6;
    const int col0 = blockIdx.x * CB;

    float top[TPT][CB], bot[TPT][CB];
    // round 0: position q holds player q
#pragma unroll
    for (int u = 0; u < TPT; ++u) {
        int g = tid * TPT + u;
        int rowT = g;
        int rowB = (g == 0) ? (NDIM - 1) : (NR - g);
#pragma unroll
        for (int c = 0; c < CB; ++c) {
            top[u][c] = (rowT == col0 + c) ? 1.f : 0.f;
            bot[u][c] = (rowB == col0 + c) ? 1.f : 0.f;
        }
    }

    float2 csCur[TPT], csNext[TPT];
    if (USE_CS) {
        const float4* p = (const float4*)(cs + tid * TPT);
#pragma unroll
        for (int q = 0; q < TPT / 2; ++q) {
            float4 v = p[q];
            csCur[2 * q]     = make_float2(v.x, v.y);
            csCur[2 * q + 1] = make_float2(v.z, v.w);
        }
    }

    for (int r = 0; r < NR; ++r) {
        if (USE_CS && (r + 1 < NR)) {
            const float4* p =
                (const float4*)(cs + (size_t)(r + 1) * NPAIRS + tid * TPT);
#pragma unroll
            for (int q = 0; q < TPT / 2; ++q) {
                float4 v = p[q];
                csNext[2 * q]     = make_float2(v.x, v.y);
                csNext[2 * q + 1] = make_float2(v.z, v.w);
            }
        }

        float na0[CB], carry[CB];
#pragma unroll
        for (int u = 0; u < TPT; ++u) {
            float c_, s_;
            if (USE_CS) {
                c_ = csCur[u].x; s_ = csCur[u].y;
            } else {
                int g = tid * TPT + u;
                int aP = r + g; if (aP >= NR) aP -= NR;
                int bP;
                if (g == 0) bP = NDIM - 1;
                else { bP = r - g; if (bP < 0) bP += NR; }
                int i = aP < bP ? aP : bP;
                int j = aP < bP ? bP : aP;
                int t = i * NDIM - (i * (i + 1)) / 2 + (j - i - 1);
                float th = thetas[t];
                float s, c;
                sincosf(th, &s, &c);
                c_ = c; s_ = (aP < bP) ? s : -s;
            }
            float na[CB], nb[CB];
#pragma unroll
            for (int c = 0; c < CB; ++c) {
                float a = top[u][c], b = bot[u][c];
                na[c] = c_ * a - s_ * b;
                nb[c] = s_ * a + c_ * b;
            }
            if (u == 0) {
#pragma unroll
                for (int c = 0; c < CB; ++c) { na0[c] = na[c]; carry[c] = nb[c]; }
            } else {
#pragma unroll
                for (int c = 0; c < CB; ++c) {
                    top[u - 1][c] = na[c];     // top shifts left
                    bot[u][c]     = carry[c];  // bottom shifts right
                    carry[c]      = nb[c];
                }
            }
        }
        // carry = nb(table 8t+7); na0 = na(table 8t)
        float t7[CB], b0[CB];
#pragma unroll
        for (int c = 0; c < CB; ++c) {
            t7[c] = __shfl_down(na0[c], 1);   // from lane+1: its na0
            b0[c] = __shfl_up(carry[c], 1);   // from lane-1: its nb7
        }
        const int pb = r & 1;
        if (lane == 0) {
#pragma unroll
            for (int c = 0; c < CB; ++c) naBuf[pb][wave][c] = na0[c];
        }
        if (lane == 63) {
#pragma unroll
            for (int c = 0; c < CB; ++c) nbBuf[pb][wave][c] = carry[c];
        }
        __syncthreads();
        if (lane == 63) {
            if (wave < 3) {
#pragma unroll
                for (int c = 0; c < CB; ++c) t7[c] = naBuf[pb][wave + 1][c];
            } else {
                // global thread 255: top[2047] <- own nb(2047)
#pragma unroll
                for (int c = 0; c < CB; ++c) t7[c] = carry[c];
            }
        }
        if (lane == 0 && wave > 0) {
#pragma unroll
            for (int c = 0; c < CB; ++c) b0[c] = nbBuf[pb][wave - 1][c];
        }
#pragma unroll
        for (int c = 0; c < CB; ++c) top[TPT - 1][c] = t7[c];
        if (tid == 0) {
            // bot[1] currently holds nb(0): fixed seat keeps it; bot[1] <- na(0)
#pragma unroll
            for (int c = 0; c < CB; ++c) { bot[0][c] = bot[1][c]; bot[1][c] = na0[c]; }
        } else {
#pragma unroll
            for (int c = 0; c < CB; ++c) bot[0][c] = b0[c];
        }
        if (USE_CS) {
#pragma unroll
            for (int u = 0; u < TPT; ++u) csCur[u] = csNext[u];
        }
    }

    // After NR shifts, position q holds player q again:
    // top[g] = row g; bot[g] = row 4095-g (g>=1); bot[0] = row 4095.
#pragma unroll
    for (int u = 0; u < TPT; ++u) {
        int g = tid * TPT + u;
        int rowT = g;
        int rowB = (g == 0) ? (NDIM - 1) : (NR - g);
        float4* oT = (float4*)&out[(size_t)rowT * NDIM + col0];
        oT[0] = make_float4(top[u][0], top[u][1], top[u][2], top[u][3]);
        oT[1] = make_float4(top[u][4], top[u][5], top[u][6], top[u][7]);
        float4* oB = (float4*)&out[(size_t)rowB * NDIM + col0];
        oB[0] = make_float4(bot[u][0], bot[u][1], bot[u][2], bot[u][3]);
        oB[1] = make_float4(bot[u][4], bot[u][5], bot[u][6], bot[u][7]);
    }
}

extern "C" void kernel_launch(void* const* d_in, const int* in_sizes, int n_in,
                              void* d_out, int out_size, void* d_ws, size_t ws_size,
                              hipStream_t stream) {
    const float* thetas      = (const float*)d_in[0];
    const int*   round_theta = (const int*)d_in[3];
    float*       out         = (float*)d_out;

    const int total = NR * NPAIRS;
    const size_t need = (size_t)total * sizeof(float2);

    if (ws_size >= need) {
        float2* cs = (float2*)d_ws;
        cs_precompute<<<(total + 255) / 256, 256, 0, stream>>>(
            thetas, round_theta, cs, total);
        rotmat_systolic<true><<<NDIM / CB, NTHREADS, 0, stream>>>(cs, thetas, out);
    } else {
        rotmat_systolic<false><<<NDIM / CB, NTHREADS, 0, stream>>>(nullptr, thetas, out);
    }
}